// Round 8
// baseline (121.119 us; speedup 1.0000x reference)
//
#include <hip/hip_runtime.h>
#include <hip/hip_bf16.h>

typedef unsigned short u16;
typedef __attribute__((ext_vector_type(8))) __bf16 bf16x8;
typedef __attribute__((ext_vector_type(8))) unsigned short u16x8;
typedef __attribute__((ext_vector_type(4))) float f32x4;
typedef __attribute__((ext_vector_type(4))) unsigned short u16x4;

#define SEQ 4096
#define DIM 1024
#define NH 16
#define HD 64
#define WIN 256
#define NT32 (SEQ / 32)
#define NKT 32  // K-tiles of 32 in K=1024

__device__ inline u16 f2bf(float f) {
  __hip_bfloat16 h = __float2bfloat16(f);
  return __builtin_bit_cast(u16, h);
}

__device__ inline void gload_lds16(const void* g, void* l) {
  auto gp = reinterpret_cast<__attribute__((address_space(1))) unsigned int*>(
      reinterpret_cast<unsigned long long>(g));
  auto lp = reinterpret_cast<__attribute__((address_space(3))) unsigned int*>(
      reinterpret_cast<unsigned long long>(l));
  __builtin_amdgcn_global_load_lds(gp, lp, 16, 0, 0);
}

__global__ __launch_bounds__(256) void cast4(const float* __restrict__ in,
                                             u16* __restrict__ out, int n) {
  int i = (blockIdx.x * 256 + threadIdx.x) * 4;
  if (i >= n) return;
  const float4 v = *reinterpret_cast<const float4*>(in + i);
  u16x4 r;
  r.x = f2bf(v.x); r.y = f2bf(v.y); r.z = f2bf(v.z); r.w = f2bf(v.w);
  *reinterpret_cast<u16x4*>(out + i) = r;
}

// Fused cast of the 3 weight matrices into Wcat.
__global__ __launch_bounds__(256) void cast_w3(const float* __restrict__ w0, const float* __restrict__ w1,
                                               const float* __restrict__ w2, u16* __restrict__ out) {
  int i = (blockIdx.x * 256 + threadIdx.x) * 4;
  const int seg = i >> 20;                 // 0,1,2
  const int loc = i & ((1 << 20) - 1);
  const float* src = (seg == 0) ? w0 : (seg == 1) ? w1 : w2;
  const float4 v = *reinterpret_cast<const float4*>(src + loc);
  u16x4 r;
  r.x = f2bf(v.x); r.y = f2bf(v.y); r.z = f2bf(v.z); r.w = f2bf(v.w);
  *reinterpret_cast<u16x4*>(out + i) = r;
}

// Pack 3 bias vectors (DIM each) into one f32 array.
__global__ __launch_bounds__(256) void pack_bias(const float* __restrict__ b0, const float* __restrict__ b1,
                                                 const float* __restrict__ b2, float* __restrict__ out) {
  int i = blockIdx.x * 256 + threadIdx.x;  // 0..3071
  const int seg = i >> 10, loc = i & 1023;
  out[i] = (seg == 0) ? b0[loc] : (seg == 1) ? b1[loc] : b2[loc];
}

// Stage one 256x32 A-panel tile + 256x32 B-panel tile into LDS slot.
__device__ __forceinline__ void stage_tile(const u16* __restrict__ A, const u16* __restrict__ B,
                                           int bm, int bn, u16* sa, u16* sb, int kt, int tid) {
  const int k0 = kt * 32;
#pragma unroll
  for (int l = 0; l < 2; ++l) {
    const int li = l * 512 + tid;         // 1024 chunks of 16B per matrix
    const int r = li >> 2, c = (li & 3) * 8;
    gload_lds16(A + (size_t)(bm + r) * DIM + k0 + c, sa + li * 8);
    gload_lds16(B + (size_t)(bn + r) * DIM + k0 + c, sb + li * 8);
  }
}

// Fused QKV projection, tri-buffered counted-vmcnt pipeline (T3/T4).
// Cols 0-1023    -> Qh [NH][S][64]  (x 0.125/ln2, exp2 trick)
// Cols 1024-2047 -> Kh [NH][S][64]
// Cols 2048-3071 -> Vtile [NH][S/32][64][32], key order sigma-PERMUTED within each 32-tile
//                   (pos = k<16 ? (k>>2)*8+(k&3) : ((k-16)>>2)*8+4+(k&3)) to match the
//                   zero-shuffle PV fragment in lf_attn.
__global__ __launch_bounds__(512, 2) void gemm_qkv(const u16* __restrict__ A, const u16* __restrict__ B,
                                                   const float* __restrict__ bias,
                                                   u16* __restrict__ Qh, u16* __restrict__ Kh,
                                                   u16* __restrict__ Vtile) {
  __shared__ __align__(16) u16 SA[3][256 * 32];
  __shared__ __align__(16) u16 SB[3][256 * 32];
  const int nwgx = gridDim.x;                        // 12
  const int orig = blockIdx.y * nwgx + blockIdx.x;   // 0..191
  const int cpx = (nwgx * gridDim.y) >> 3;           // 24
  const int wgid = (orig & 7) * cpx + (orig >> 3);   // bijective (192%8==0)
  const int bm = (wgid / nwgx) * 256, bn = (wgid % nwgx) * 256;
  const int tid = threadIdx.x;
  const int lane = tid & 63, wid = tid >> 6;
  const int lrow = lane & 15, lgrp = lane >> 4;
  const int wr = (wid >> 2) * 128, wc = (wid & 3) * 64;

  f32x4 acc[8][4];
  const f32x4 zero = {0.f, 0.f, 0.f, 0.f};
#pragma unroll
  for (int m = 0; m < 8; ++m)
#pragma unroll
    for (int n = 0; n < 4; ++n) acc[m][n] = zero;

  stage_tile(A, B, bm, bn, SA[0], SB[0], 0, tid);
  stage_tile(A, B, bm, bn, SA[1], SB[1], 1, tid);
  asm volatile("s_waitcnt vmcnt(4)" ::: "memory");   // tile0 landed (tile1 may fly)
  asm volatile("s_barrier" ::: "memory");

  for (int t = 0; t < NKT; ++t) {
    const int s = t % 3;
    if (t + 2 < NKT) stage_tile(A, B, bm, bn, SA[(t + 2) % 3], SB[(t + 2) % 3], t + 2, tid);
    bf16x8 af[8], bfr[4];
#pragma unroll
    for (int m = 0; m < 8; ++m)
      af[m] = *reinterpret_cast<const bf16x8*>(&SA[s][(wr + m * 16 + lrow) * 32 + lgrp * 8]);
#pragma unroll
    for (int n = 0; n < 4; ++n)
      bfr[n] = *reinterpret_cast<const bf16x8*>(&SB[s][(wc + n * 16 + lrow) * 32 + lgrp * 8]);
    __builtin_amdgcn_s_setprio(1);
#pragma unroll
    for (int m = 0; m < 8; ++m)
#pragma unroll
      for (int n = 0; n < 4; ++n)
        acc[m][n] = __builtin_amdgcn_mfma_f32_16x16x32_bf16(af[m], bfr[n], acc[m][n], 0, 0, 0);
    __builtin_amdgcn_s_setprio(0);
    if (t + 2 < NKT) { asm volatile("s_waitcnt vmcnt(4)" ::: "memory"); }
    else if (t + 1 < NKT) { asm volatile("s_waitcnt vmcnt(0)" ::: "memory"); }
    asm volatile("s_barrier" ::: "memory");
  }

#pragma unroll
  for (int m = 0; m < 8; ++m)
#pragma unroll
    for (int n = 0; n < 4; ++n) {
      const int row0 = bm + wr + m * 16 + lgrp * 4;
      const int colg = bn + wc + n * 16 + lrow;
      const float b = bias[colg];
      if (bn < 2048) {
        u16* dst = (bn < 1024) ? Qh : Kh;
        const float sc = (bn < 1024) ? 0.18033688f : 1.0f;  // 0.125/ln2 (exp2 trick)
        const int hh = (colg & 1023) >> 6;
        const int dd = colg & 63;
#pragma unroll
        for (int r = 0; r < 4; ++r)
          dst[((size_t)hh * SEQ + row0 + r) * HD + dd] = f2bf((acc[m][n][r] + b) * sc);
      } else {
        const int dv = colg - 2048;
        const int hh = dv >> 6, dd = dv & 63;
        const int k5 = row0 & 31;            // 4-aligned key offset within 32-tile
        const int pos = (k5 < 16) ? ((k5 >> 2) * 8) : (((k5 - 16) >> 2) * 8 + 4);
        u16x4 pk;
#pragma unroll
        for (int r = 0; r < 4; ++r) pk[r] = f2bf(acc[m][n][r] + b);
        u16* vt = Vtile + ((((size_t)hh * NT32 + (row0 >> 5)) * HD + dd) << 5) + pos;
        *reinterpret_cast<u16x4*>(vt) = pk;
      }
    }
}

// Banded flash attention, deferred softmax (exp2), split-K wave pairs,
// SWAPPED QK^T (S^T = K.Q^T) -> P is lane-local for PV: zero LDS / zero shuffles
// in the main loop. V consumed in sigma-permuted key order (see gemm_qkv).
__global__ __launch_bounds__(256, 4) void lf_attn(const u16* __restrict__ Qh, const u16* __restrict__ Kh,
                                                  const u16* __restrict__ Vtile, const float* __restrict__ amask,
                                                  float* __restrict__ out) {
  const int nwgx = gridDim.x;                       // 128
  const int nwg = nwgx * gridDim.y;                 // 2048
  const int orig = blockIdx.y * nwgx + blockIdx.x;
  const int cpx = nwg >> 3;                         // 256
  const int wgid = (orig & 7) * cpx + (orig >> 3);  // bijective (2048%8==0)
  const int h = wgid / nwgx;
  const int q0 = (wgid % nwgx) * 32;
  const int tid = threadIdx.x;
  const int wid = tid >> 6, lane = tid & 63;
  const int qt = wid & 1, kh = wid >> 1;
  const int lrow = lane & 15, lgrp = lane >> 4;
  const int qw = q0 + qt * 16;
  __shared__ __align__(16) float Ocmb[2][16][64];
  __shared__ float Pscmb[2][16];

  bf16x8 qf0, qf1;
  {
    const u16* qbase = Qh + ((size_t)h * SEQ + qw + lrow) * HD + lgrp * 8;
    qf0 = *reinterpret_cast<const bf16x8*>(qbase);
    qf1 = *reinterpret_cast<const bf16x8*>(qbase + 32);
  }
  const f32x4 zero = {0.f, 0.f, 0.f, 0.f};
  f32x4 o_acc[4];
  float psum = 0.f;
#pragma unroll
  for (int g = 0; g < 4; ++g) o_acc[g] = zero;

  int kstart = qw - WIN; if (kstart < 0) kstart = 0; kstart &= ~31;
  int kend = qw + 15 + WIN + 1; kend = (kend + 31) & ~31; if (kend > SEQ) kend = SEQ;
  const int nt = (kend - kstart) >> 5;
  const int hf = (nt + 1) >> 1;
  const int tbeg = kh ? hf : 0;
  const int tend = kh ? nt : hf;

  const int q_abs = qw + lrow;  // this lane's q row (swapped layout)

  // Pointer bases for tile tbeg; advance 2048 elements (= 32 keys) per tile.
  const u16* kp = Kh + ((size_t)h * SEQ + kstart + tbeg * 32 + lrow) * HD + lgrp * 8;
  const u16* vp = Vtile + ((size_t)h * NT32 + (kstart >> 5) + tbeg) * (HD * 32) + lrow * 32 + lgrp * 8;

  bf16x8 kf0, kf1, kf2, kf3, vf0, vf1, vf2, vf3;
  kf0 = *reinterpret_cast<const bf16x8*>(kp);
  kf1 = *reinterpret_cast<const bf16x8*>(kp + 32);
  kf2 = *reinterpret_cast<const bf16x8*>(kp + 16 * HD);
  kf3 = *reinterpret_cast<const bf16x8*>(kp + 16 * HD + 32);
  vf0 = *reinterpret_cast<const bf16x8*>(vp);
  vf1 = *reinterpret_cast<const bf16x8*>(vp + 512);
  vf2 = *reinterpret_cast<const bf16x8*>(vp + 1024);
  vf3 = *reinterpret_cast<const bf16x8*>(vp + 1536);

  for (int t = tbeg; t < tend; ++t) {
    const int kt = kstart + t * 32;
    kp += 2048; vp += 2048;
    const bool more = (t + 1 < tend);   // wave-uniform
    bf16x8 kn0, kn1, kn2, kn3, vn0, vn1, vn2, vn3;
    if (more) {  // 1-deep register prefetch
      kn0 = *reinterpret_cast<const bf16x8*>(kp);
      kn1 = *reinterpret_cast<const bf16x8*>(kp + 32);
      kn2 = *reinterpret_cast<const bf16x8*>(kp + 16 * HD);
      kn3 = *reinterpret_cast<const bf16x8*>(kp + 16 * HD + 32);
      vn0 = *reinterpret_cast<const bf16x8*>(vp);
      vn1 = *reinterpret_cast<const bf16x8*>(vp + 512);
      vn2 = *reinterpret_cast<const bf16x8*>(vp + 1024);
      vn3 = *reinterpret_cast<const bf16x8*>(vp + 1536);
    }
    // Swapped score MFMAs: s0[r] = S[key=kt+lgrp*4+r][q=q_abs], s1: +16 keys.
    f32x4 s0 = zero, s1 = zero;
    s0 = __builtin_amdgcn_mfma_f32_16x16x32_bf16(kf0, qf0, s0, 0, 0, 0);
    s0 = __builtin_amdgcn_mfma_f32_16x16x32_bf16(kf1, qf1, s0, 0, 0, 0);
    s1 = __builtin_amdgcn_mfma_f32_16x16x32_bf16(kf2, qf0, s1, 0, 0, 0);
    s1 = __builtin_amdgcn_mfma_f32_16x16x32_bf16(kf3, qf1, s1, 0, 0, 0);

    // attention-mask values for this lane's 8 keys (two contiguous float4s)
    const float4 amA = *reinterpret_cast<const float4*>(amask + kt + lgrp * 4);
    const float4 amB = *reinterpret_cast<const float4*>(amask + kt + 16 + lgrp * 4);
    const float amAv[4] = {amA.x, amA.y, amA.z, amA.w};
    const float amBv[4] = {amB.x, amB.y, amB.z, amB.w};

    u16x8 pu;
    if (kt >= qw - 241 && kt <= qw + 225) {
      // whole tile inside band for every (q,key) of this wave: no validity selects
#pragma unroll
      for (int r = 0; r < 4; ++r) {
        const float m0 = (amAv[r] != 0.f) ? -14426.95f : 0.f;
        const float m1 = (amBv[r] != 0.f) ? -14426.95f : 0.f;
        const float e0 = __builtin_amdgcn_exp2f(s0[r] + m0);
        const float e1 = __builtin_amdgcn_exp2f(s1[r] + m1);
        psum += e0 + e1;
        pu[r] = f2bf(e0);
        pu[4 + r] = f2bf(e1);
      }
    } else {
#pragma unroll
      for (int r = 0; r < 4; ++r) {
        const int key0 = kt + lgrp * 4 + r;
        const int d0 = key0 - q_abs + WIN;   // valid iff 0 <= d0 <= 2*WIN
        const float m0 = (amAv[r] != 0.f) ? -14426.95f : 0.f;
        const float m1 = (amBv[r] != 0.f) ? -14426.95f : 0.f;
        const float e0 = ((unsigned)d0 <= 2u * WIN) ? __builtin_amdgcn_exp2f(s0[r] + m0) : 0.f;
        const float e1 = ((unsigned)(d0 + 16) <= 2u * WIN) ? __builtin_amdgcn_exp2f(s1[r] + m1) : 0.f;
        psum += e0 + e1;
        pu[r] = f2bf(e0);
        pu[4 + r] = f2bf(e1);
      }
    }
    const bf16x8 pa = __builtin_bit_cast(bf16x8, pu);
    o_acc[0] = __builtin_amdgcn_mfma_f32_16x16x32_bf16(pa, vf0, o_acc[0], 0, 0, 0);
    o_acc[1] = __builtin_amdgcn_mfma_f32_16x16x32_bf16(pa, vf1, o_acc[1], 0, 0, 0);
    o_acc[2] = __builtin_amdgcn_mfma_f32_16x16x32_bf16(pa, vf2, o_acc[2], 0, 0, 0);
    o_acc[3] = __builtin_amdgcn_mfma_f32_16x16x32_bf16(pa, vf3, o_acc[3], 0, 0, 0);
    if (more) {
      kf0 = kn0; kf1 = kn1; kf2 = kn2; kf3 = kn3;
      vf0 = vn0; vf1 = vn1; vf2 = vn2; vf3 = vn3;
    }
  }

  // psum holds this lane's partial row-sum for q = q_abs (spread over lgrp);
  // reduce across the 4 lgrp copies.
  psum += __shfl_xor(psum, 16);
  psum += __shfl_xor(psum, 32);

  // Combine the two key-halves of each q-tile.
  if (kh == 1) {
#pragma unroll
    for (int g = 0; g < 4; ++g)
#pragma unroll
      for (int r = 0; r < 4; ++r)
        Ocmb[qt][lgrp * 4 + r][g * 16 + lrow] = o_acc[g][r];
    if (lane < 16) Pscmb[qt][lane] = psum;
  }
  __syncthreads();
  if (kh == 0) {
    const float total = psum + Pscmb[qt][lrow];  // full row-sum for q = q_abs
    float psr[4];
#pragma unroll
    for (int r = 0; r < 4; ++r) psr[r] = __shfl(total, lgrp * 4 + r, 64);
#pragma unroll
    for (int g = 0; g < 4; ++g)
#pragma unroll
      for (int r = 0; r < 4; ++r) {
        const int row = qw + lgrp * 4 + r;
        const float o = o_acc[g][r] + Ocmb[qt][lgrp * 4 + r][g * 16 + lrow];
        out[(size_t)row * DIM + h * HD + g * 16 + lrow] = o / psr[r];
      }
  }
}

extern "C" void kernel_launch(void* const* d_in, const int* in_sizes, int n_in,
                              void* d_out, int out_size, void* d_ws, size_t ws_size,
                              hipStream_t stream) {
  const float* hsrc  = (const float*)d_in[0];
  const float* amask = (const float*)d_in[1];
  const float* Wq = (const float*)d_in[3];
  const float* bq = (const float*)d_in[4];
  const float* Wk = (const float*)d_in[5];
  const float* bk = (const float*)d_in[6];
  const float* Wv = (const float*)d_in[7];
  const float* bv = (const float*)d_in[8];
  float* out = (float*)d_out;
  char* ws = (char*)d_ws;
  const size_t MB = 1024 * 1024;
  u16*   Hb      = (u16*)(ws);                 // 8 MB: hidden bf16 [4096][1024]
  u16*   Wcat    = (u16*)(ws + 8 * MB);        // 6 MB: [3072][1024] bf16 (Wq|Wk|Wv)
  float* biascat = (float*)(ws + 14 * MB);     // 12 KB: [3072] f32
  u16*   Qh      = (u16*)(ws + 15 * MB);       // 8 MB: [NH][S][64] (pre-scaled by 0.125/ln2)
  u16*   Kh      = (u16*)(ws + 23 * MB);       // 8 MB: [NH][S][64]
  u16*   Vtile   = (u16*)(ws + 31 * MB);       // 8 MB: [NH][S/32][64][32] sigma-permuted

  cast4<<<4096, 256, 0, stream>>>(hsrc, Hb, SEQ * DIM);
  cast_w3<<<3072, 256, 0, stream>>>(Wq, Wk, Wv, Wcat);
  pack_bias<<<12, 256, 0, stream>>>(bq, bk, bv, biascat);

  dim3 gq(3 * DIM / 256, SEQ / 256);  // (12, 16)
  gemm_qkv<<<gq, 512, 0, stream>>>(Hb, Wcat, biascat, Qh, Kh, Vtile);

  dim3 ga(SEQ / 32, NH);              // (128, 16)
  lf_attn<<<ga, 256, 0, stream>>>(Qh, Kh, Vtile, amask, out);
}

// Round 9
// 105.233 us; speedup vs baseline: 1.1510x; 1.1510x over previous
//
#include <hip/hip_runtime.h>
#include <hip/hip_bf16.h>

typedef unsigned short u16;
typedef __attribute__((ext_vector_type(8))) __bf16 bf16x8;
typedef __attribute__((ext_vector_type(8))) unsigned short u16x8;
typedef __attribute__((ext_vector_type(4))) float f32x4;
typedef __attribute__((ext_vector_type(4))) unsigned short u16x4;

#define SEQ 4096
#define DIM 1024
#define NH 16
#define HD 64
#define WIN 256
#define NT32 (SEQ / 32)
#define NKT 32  // K-tiles of 32 in K=1024

__device__ inline u16 f2bf(float f) {
  __hip_bfloat16 h = __float2bfloat16(f);
  return __builtin_bit_cast(u16, h);
}

__device__ inline void gload_lds16(const void* g, void* l) {
  auto gp = reinterpret_cast<__attribute__((address_space(1))) unsigned int*>(
      reinterpret_cast<unsigned long long>(g));
  auto lp = reinterpret_cast<__attribute__((address_space(3))) unsigned int*>(
      reinterpret_cast<unsigned long long>(l));
  __builtin_amdgcn_global_load_lds(gp, lp, 16, 0, 0);
}

__global__ __launch_bounds__(256) void cast4(const float* __restrict__ in,
                                             u16* __restrict__ out, int n) {
  int i = (blockIdx.x * 256 + threadIdx.x) * 4;
  if (i >= n) return;
  const float4 v = *reinterpret_cast<const float4*>(in + i);
  u16x4 r;
  r.x = f2bf(v.x); r.y = f2bf(v.y); r.z = f2bf(v.z); r.w = f2bf(v.w);
  *reinterpret_cast<u16x4*>(out + i) = r;
}

// Fused cast of the 3 weight matrices into Wcat.
__global__ __launch_bounds__(256) void cast_w3(const float* __restrict__ w0, const float* __restrict__ w1,
                                               const float* __restrict__ w2, u16* __restrict__ out) {
  int i = (blockIdx.x * 256 + threadIdx.x) * 4;
  const int seg = i >> 20;                 // 0,1,2
  const int loc = i & ((1 << 20) - 1);
  const float* src = (seg == 0) ? w0 : (seg == 1) ? w1 : w2;
  const float4 v = *reinterpret_cast<const float4*>(src + loc);
  u16x4 r;
  r.x = f2bf(v.x); r.y = f2bf(v.y); r.z = f2bf(v.z); r.w = f2bf(v.w);
  *reinterpret_cast<u16x4*>(out + i) = r;
}

// Pack 3 bias vectors (DIM each) into one f32 array.
__global__ __launch_bounds__(256) void pack_bias(const float* __restrict__ b0, const float* __restrict__ b1,
                                                 const float* __restrict__ b2, float* __restrict__ out) {
  int i = blockIdx.x * 256 + threadIdx.x;  // 0..3071
  const int seg = i >> 10, loc = i & 1023;
  out[i] = (seg == 0) ? b0[loc] : (seg == 1) ? b1[loc] : b2[loc];
}

// Stage one 256x32 A-panel tile + 256x32 B-panel tile into LDS slot.
__device__ __forceinline__ void stage_tile(const u16* __restrict__ A, const u16* __restrict__ B,
                                           int bm, int bn, u16* sa, u16* sb, int kt, int tid) {
  const int k0 = kt * 32;
#pragma unroll
  for (int l = 0; l < 2; ++l) {
    const int li = l * 512 + tid;         // 1024 chunks of 16B per matrix
    const int r = li >> 2, c = (li & 3) * 8;
    gload_lds16(A + (size_t)(bm + r) * DIM + k0 + c, sa + li * 8);
    gload_lds16(B + (size_t)(bn + r) * DIM + k0 + c, sb + li * 8);
  }
}

// Fused QKV projection, tri-buffered counted-vmcnt pipeline (T3/T4).
// Cols 0-1023    -> Qh [NH][S][64]  (x 0.125/ln2, exp2 trick)
// Cols 1024-2047 -> Kh [NH][S][64]
// Cols 2048-3071 -> Vtile [NH][S/32][64][32], key order sigma-PERMUTED within each 32-tile
//                   (pos = k<16 ? (k>>2)*8+(k&3) : ((k-16)>>2)*8+4+(k&3)) to match the
//                   zero-shuffle PV fragment in lf_attn.
__global__ __launch_bounds__(512, 2) void gemm_qkv(const u16* __restrict__ A, const u16* __restrict__ B,
                                                   const float* __restrict__ bias,
                                                   u16* __restrict__ Qh, u16* __restrict__ Kh,
                                                   u16* __restrict__ Vtile) {
  __shared__ __align__(16) u16 SA[3][256 * 32];
  __shared__ __align__(16) u16 SB[3][256 * 32];
  const int nwgx = gridDim.x;                        // 12
  const int orig = blockIdx.y * nwgx + blockIdx.x;   // 0..191
  const int cpx = (nwgx * gridDim.y) >> 3;           // 24
  const int wgid = (orig & 7) * cpx + (orig >> 3);   // bijective (192%8==0)
  const int bm = (wgid / nwgx) * 256, bn = (wgid % nwgx) * 256;
  const int tid = threadIdx.x;
  const int lane = tid & 63, wid = tid >> 6;
  const int lrow = lane & 15, lgrp = lane >> 4;
  const int wr = (wid >> 2) * 128, wc = (wid & 3) * 64;

  f32x4 acc[8][4];
  const f32x4 zero = {0.f, 0.f, 0.f, 0.f};
#pragma unroll
  for (int m = 0; m < 8; ++m)
#pragma unroll
    for (int n = 0; n < 4; ++n) acc[m][n] = zero;

  stage_tile(A, B, bm, bn, SA[0], SB[0], 0, tid);
  stage_tile(A, B, bm, bn, SA[1], SB[1], 1, tid);
  asm volatile("s_waitcnt vmcnt(4)" ::: "memory");   // tile0 landed (tile1 may fly)
  asm volatile("s_barrier" ::: "memory");

  for (int t = 0; t < NKT; ++t) {
    const int s = t % 3;
    if (t + 2 < NKT) stage_tile(A, B, bm, bn, SA[(t + 2) % 3], SB[(t + 2) % 3], t + 2, tid);
    bf16x8 af[8], bfr[4];
#pragma unroll
    for (int m = 0; m < 8; ++m)
      af[m] = *reinterpret_cast<const bf16x8*>(&SA[s][(wr + m * 16 + lrow) * 32 + lgrp * 8]);
#pragma unroll
    for (int n = 0; n < 4; ++n)
      bfr[n] = *reinterpret_cast<const bf16x8*>(&SB[s][(wc + n * 16 + lrow) * 32 + lgrp * 8]);
    __builtin_amdgcn_s_setprio(1);
#pragma unroll
    for (int m = 0; m < 8; ++m)
#pragma unroll
      for (int n = 0; n < 4; ++n)
        acc[m][n] = __builtin_amdgcn_mfma_f32_16x16x32_bf16(af[m], bfr[n], acc[m][n], 0, 0, 0);
    __builtin_amdgcn_s_setprio(0);
    if (t + 2 < NKT) { asm volatile("s_waitcnt vmcnt(4)" ::: "memory"); }
    else if (t + 1 < NKT) { asm volatile("s_waitcnt vmcnt(0)" ::: "memory"); }
    asm volatile("s_barrier" ::: "memory");
  }

#pragma unroll
  for (int m = 0; m < 8; ++m)
#pragma unroll
    for (int n = 0; n < 4; ++n) {
      const int row0 = bm + wr + m * 16 + lgrp * 4;
      const int colg = bn + wc + n * 16 + lrow;
      const float b = bias[colg];
      if (bn < 2048) {
        u16* dst = (bn < 1024) ? Qh : Kh;
        const float sc = (bn < 1024) ? 0.18033688f : 1.0f;  // 0.125/ln2 (exp2 trick)
        const int hh = (colg & 1023) >> 6;
        const int dd = colg & 63;
#pragma unroll
        for (int r = 0; r < 4; ++r)
          dst[((size_t)hh * SEQ + row0 + r) * HD + dd] = f2bf((acc[m][n][r] + b) * sc);
      } else {
        const int dv = colg - 2048;
        const int hh = dv >> 6, dd = dv & 63;
        const int k5 = row0 & 31;            // 4-aligned key offset within 32-tile
        const int pos = (k5 < 16) ? ((k5 >> 2) * 8) : (((k5 - 16) >> 2) * 8 + 4);
        u16x4 pk;
#pragma unroll
        for (int r = 0; r < 4; ++r) pk[r] = f2bf(acc[m][n][r] + b);
        u16* vt = Vtile + ((((size_t)hh * NT32 + (row0 >> 5)) * HD + dd) << 5) + pos;
        *reinterpret_cast<u16x4*>(vt) = pk;
      }
    }
}

// Banded flash attention, deferred softmax (exp2), swapped QK^T -> zero LDS /
// zero shuffles in the main loop. One wave = one 16-row q-tile, full key range,
// no block synchronization. V consumed in sigma-permuted key order.
__global__ __launch_bounds__(256) void lf_attn(const u16* __restrict__ Qh, const u16* __restrict__ Kh,
                                               const u16* __restrict__ Vtile, const float* __restrict__ amask,
                                               float* __restrict__ out) {
  const int nwgx = gridDim.x;                       // 64
  const int nwg = nwgx * gridDim.y;                 // 1024
  const int orig = blockIdx.y * nwgx + blockIdx.x;
  const int cpx = nwg >> 3;                         // 128
  const int wgid = (orig & 7) * cpx + (orig >> 3);  // bijective (1024%8==0)
  const int h = wgid / nwgx;
  const int q0 = (wgid % nwgx) * 64;
  const int tid = threadIdx.x;
  const int wid = tid >> 6, lane = tid & 63;
  const int lrow = lane & 15, lgrp = lane >> 4;
  const int qw = q0 + wid * 16;                     // this wave's 16 q-rows

  bf16x8 qf0, qf1;
  {
    const u16* qbase = Qh + ((size_t)h * SEQ + qw + lrow) * HD + lgrp * 8;
    qf0 = *reinterpret_cast<const bf16x8*>(qbase);
    qf1 = *reinterpret_cast<const bf16x8*>(qbase + 32);
  }
  const f32x4 zero = {0.f, 0.f, 0.f, 0.f};
  f32x4 o_acc[4];
  float psum = 0.f;
#pragma unroll
  for (int g = 0; g < 4; ++g) o_acc[g] = zero;

  int kstart = qw - WIN; if (kstart < 0) kstart = 0; kstart &= ~31;
  int kend = qw + 15 + WIN + 1; kend = (kend + 31) & ~31; if (kend > SEQ) kend = SEQ;

  const int q_abs = qw + lrow;  // this lane's q row (swapped layout)

  const u16* kp = Kh + ((size_t)h * SEQ + kstart + lrow) * HD + lgrp * 8;
  const u16* vp = Vtile + ((size_t)h * NT32 + (kstart >> 5)) * (HD * 32) + lrow * 32 + lgrp * 8;

  for (int kt = kstart; kt < kend; kt += 32) {
    const bf16x8 kf0 = *reinterpret_cast<const bf16x8*>(kp);
    const bf16x8 kf1 = *reinterpret_cast<const bf16x8*>(kp + 32);
    const bf16x8 kf2 = *reinterpret_cast<const bf16x8*>(kp + 16 * HD);
    const bf16x8 kf3 = *reinterpret_cast<const bf16x8*>(kp + 16 * HD + 32);
    const bf16x8 vf0 = *reinterpret_cast<const bf16x8*>(vp);
    const bf16x8 vf1 = *reinterpret_cast<const bf16x8*>(vp + 512);
    const bf16x8 vf2 = *reinterpret_cast<const bf16x8*>(vp + 1024);
    const bf16x8 vf3 = *reinterpret_cast<const bf16x8*>(vp + 1536);
    kp += 2048; vp += 2048;

    // Swapped score MFMAs: s0[r] = S[key=kt+lgrp*4+r][q=q_abs], s1: +16 keys.
    f32x4 s0 = zero, s1 = zero;
    s0 = __builtin_amdgcn_mfma_f32_16x16x32_bf16(kf0, qf0, s0, 0, 0, 0);
    s0 = __builtin_amdgcn_mfma_f32_16x16x32_bf16(kf1, qf1, s0, 0, 0, 0);
    s1 = __builtin_amdgcn_mfma_f32_16x16x32_bf16(kf2, qf0, s1, 0, 0, 0);
    s1 = __builtin_amdgcn_mfma_f32_16x16x32_bf16(kf3, qf1, s1, 0, 0, 0);

    // attention-mask values for this lane's 8 keys (two contiguous float4s)
    const float4 amA = *reinterpret_cast<const float4*>(amask + kt + lgrp * 4);
    const float4 amB = *reinterpret_cast<const float4*>(amask + kt + 16 + lgrp * 4);
    const float amAv[4] = {amA.x, amA.y, amA.z, amA.w};
    const float amBv[4] = {amB.x, amB.y, amB.z, amB.w};

    u16x8 pu;
    if (kt >= qw - 241 && kt <= qw + 225) {
      // whole tile inside band for every (q,key) of this wave: no validity selects
#pragma unroll
      for (int r = 0; r < 4; ++r) {
        const float m0 = (amAv[r] != 0.f) ? -14426.95f : 0.f;
        const float m1 = (amBv[r] != 0.f) ? -14426.95f : 0.f;
        const float e0 = __builtin_amdgcn_exp2f(s0[r] + m0);
        const float e1 = __builtin_amdgcn_exp2f(s1[r] + m1);
        psum += e0 + e1;
        pu[r] = f2bf(e0);
        pu[4 + r] = f2bf(e1);
      }
    } else {
#pragma unroll
      for (int r = 0; r < 4; ++r) {
        const int key0 = kt + lgrp * 4 + r;
        const int d0 = key0 - q_abs + WIN;   // valid iff 0 <= d0 <= 2*WIN
        const float m0 = (amAv[r] != 0.f) ? -14426.95f : 0.f;
        const float m1 = (amBv[r] != 0.f) ? -14426.95f : 0.f;
        const float e0 = ((unsigned)d0 <= 2u * WIN) ? __builtin_amdgcn_exp2f(s0[r] + m0) : 0.f;
        const float e1 = ((unsigned)(d0 + 16) <= 2u * WIN) ? __builtin_amdgcn_exp2f(s1[r] + m1) : 0.f;
        psum += e0 + e1;
        pu[r] = f2bf(e0);
        pu[4 + r] = f2bf(e1);
      }
    }
    const bf16x8 pa = __builtin_bit_cast(bf16x8, pu);
    o_acc[0] = __builtin_amdgcn_mfma_f32_16x16x32_bf16(pa, vf0, o_acc[0], 0, 0, 0);
    o_acc[1] = __builtin_amdgcn_mfma_f32_16x16x32_bf16(pa, vf1, o_acc[1], 0, 0, 0);
    o_acc[2] = __builtin_amdgcn_mfma_f32_16x16x32_bf16(pa, vf2, o_acc[2], 0, 0, 0);
    o_acc[3] = __builtin_amdgcn_mfma_f32_16x16x32_bf16(pa, vf3, o_acc[3], 0, 0, 0);
  }

  // psum: partial (over this lane's lgrp key-slice) row-sum for q = q_abs.
  // The 4 lgrp copies of each q-row live at lanes lrow, lrow+16, lrow+32, lrow+48.
  psum += __shfl_xor(psum, 16);
  psum += __shfl_xor(psum, 32);

  // Redistribute: lane needs row sums for q rows lgrp*4+r (r=0..3).
  float psr[4];
#pragma unroll
  for (int r = 0; r < 4; ++r) psr[r] = __shfl(psum, lgrp * 4 + r, 64);
#pragma unroll
  for (int g = 0; g < 4; ++g)
#pragma unroll
    for (int r = 0; r < 4; ++r) {
      const int row = qw + lgrp * 4 + r;
      out[(size_t)row * DIM + h * HD + g * 16 + lrow] = o_acc[g][r] / psr[r];
    }
}

extern "C" void kernel_launch(void* const* d_in, const int* in_sizes, int n_in,
                              void* d_out, int out_size, void* d_ws, size_t ws_size,
                              hipStream_t stream) {
  const float* hsrc  = (const float*)d_in[0];
  const float* amask = (const float*)d_in[1];
  const float* Wq = (const float*)d_in[3];
  const float* bq = (const float*)d_in[4];
  const float* Wk = (const float*)d_in[5];
  const float* bk = (const float*)d_in[6];
  const float* Wv = (const float*)d_in[7];
  const float* bv = (const float*)d_in[8];
  float* out = (float*)d_out;
  char* ws = (char*)d_ws;
  const size_t MB = 1024 * 1024;
  u16*   Hb      = (u16*)(ws);                 // 8 MB: hidden bf16 [4096][1024]
  u16*   Wcat    = (u16*)(ws + 8 * MB);        // 6 MB: [3072][1024] bf16 (Wq|Wk|Wv)
  float* biascat = (float*)(ws + 14 * MB);     // 12 KB: [3072] f32
  u16*   Qh      = (u16*)(ws + 15 * MB);       // 8 MB: [NH][S][64] (pre-scaled by 0.125/ln2)
  u16*   Kh      = (u16*)(ws + 23 * MB);       // 8 MB: [NH][S][64]
  u16*   Vtile   = (u16*)(ws + 31 * MB);       // 8 MB: [NH][S/32][64][32] sigma-permuted

  cast4<<<4096, 256, 0, stream>>>(hsrc, Hb, SEQ * DIM);
  cast_w3<<<3072, 256, 0, stream>>>(Wq, Wk, Wv, Wcat);
  pack_bias<<<12, 256, 0, stream>>>(bq, bk, bv, biascat);

  dim3 gq(3 * DIM / 256, SEQ / 256);  // (12, 16)
  gemm_qkv<<<gq, 512, 0, stream>>>(Hb, Wcat, biascat, Qh, Kh, Vtile);

  dim3 ga(SEQ / 64, NH);              // (64, 16) -> 1024 blocks, 4 independent waves each
  lf_attn<<<ga, 256, 0, stream>>>(Qh, Kh, Vtile, amask, out);
}